// Round 9
// baseline (305.299 us; speedup 1.0000x reference)
//
#include <hip/hip_runtime.h>
#include <hip/hip_bf16.h>
#include <math.h>

#define NNODES 8192
#define NEDGES 131072
#define HID    512
#define UU     16
#define MM     512
#define NQS    1024   // packed q|s columns in Y

#if __has_builtin(__builtin_amdgcn_cvt_pk_f32_fp8) && __has_builtin(__builtin_amdgcn_cvt_pk_fp8_f32)
#define HAVE_FP8 1
#define KVREC  1536   // 512B k(fp8) + 1024B v(bf16)
#define KOFF_V 512
#else
#define HAVE_FP8 0
#define KVREC  2048   // 1024B k(bf16) + 1024B v(bf16)
#define KOFF_V 1024
#endif

#define KSCALE 16.0f
#define KISCALE (0.125f / 16.0f)   // score = (q . 16k) * 0.125/16

typedef __attribute__((ext_vector_type(8))) short bf16x8;
typedef __attribute__((ext_vector_type(4))) float f32x4;
typedef __attribute__((ext_vector_type(2))) float f32x2;

__device__ __forceinline__ float bf2f(ushort u) {
    return __uint_as_float(((unsigned)u) << 16);
}
__device__ __forceinline__ ushort f2bf(float f) {
    unsigned x = __float_as_uint(f);
    return (ushort)((x + 0x7fffu + ((x >> 16) & 1u)) >> 16);
}

// ------- weight transpose+convert + bias pack + scratch zeroing (fused) -------
__global__ __launch_bounds__(256) void k_wtb(
    const float* __restrict__ Wq, const float* __restrict__ Wk,
    const float* __restrict__ Wv, const float* __restrict__ Ws,
    const float* __restrict__ bq, const float* __restrict__ bk,
    const float* __restrict__ bv, const float* __restrict__ bs,
    ushort* __restrict__ Wt, float* __restrict__ bcat, int* __restrict__ zbuf)
{
    __shared__ float tile[64][65];
    int z = blockIdx.z;
    int t = threadIdx.x;
    if (z == 12) {
        int id = blockIdx.y * 8 + blockIdx.x;   // 0..63
        if (id < 24) {                          // bias pack [3][2048]
            int i = id * 256 + t;
            int l = i >> 11, j = i & 2047;
            int which = j >> 9, jj = j & 511;
            const float* b = which == 0 ? bq : which == 1 ? bk : which == 2 ? bv : bs;
            bcat[i] = b[l * HID + jj];
        } else if (id <= 56) {                  // zero cnt+cursor+done (33*512 ints)
            zbuf[(id - 24) * 512 + t * 2] = 0;
            zbuf[(id - 24) * 512 + t * 2 + 1] = 0;
        }
        return;
    }
    int l = z >> 2, which = z & 3;
    const float* src = (which == 0 ? Wq : which == 1 ? Wk : which == 2 ? Wv : Ws)
                       + (size_t)l * HID * HID;
    int k0 = blockIdx.x * 64, c0 = blockIdx.y * 64;
#pragma unroll
    for (int i = 0; i < 16; ++i) {
        int idx = i * 256 + t;
        int r = idx >> 6, c = idx & 63;
        tile[r][c] = src[(size_t)(k0 + r) * HID + c0 + c];
    }
    __syncthreads();
    ushort* dst = Wt + ((size_t)l * 2048 + which * HID + c0) * HID + k0;
#pragma unroll
    for (int i = 0; i < 16; ++i) {
        int idx = i * 256 + t;
        int r = idx >> 6, c = idx & 63;
        dst[(size_t)r * HID + c] = f2bf(tile[c][r]);
    }
}

// ------- CSR histogram with fused last-block scan -------
__global__ __launch_bounds__(256) void k_histscan(
    const int* __restrict__ dst, int* __restrict__ cnt,
    int* __restrict__ indptr, int* __restrict__ done)
{
    int e = blockIdx.x * 256 + threadIdx.x;
    atomicAdd(&cnt[dst[e]], 1);
    __threadfence();
    __shared__ int amlast;
    if (threadIdx.x == 0)
        amlast = (atomicAdd(done, 1) == (int)gridDim.x - 1);
    __syncthreads();
    if (!amlast) return;
    // this block sees all cnt updates (fenced before done increment)
    __shared__ int sums[256];
    __shared__ int offs[256];
    int t = threadIdx.x;
    int base = t * 32;
    int s = 0;
    for (int i = 0; i < 32; ++i) s += cnt[base + i];
    sums[t] = s;
    __syncthreads();
    if (t == 0) {
        int run = 0;
        for (int i = 0; i < 256; ++i) { offs[i] = run; run += sums[i]; }
    }
    __syncthreads();
    int off = offs[t];
    for (int i = 0; i < 32; ++i) { indptr[base + i] = off; off += cnt[base + i]; }
    if (t == 255) indptr[NNODES] = off;
}

// ------- fused: edge scatter (blocks 0..511) + layer-0 linear (blocks 512..8703) -------
__global__ __launch_bounds__(256) void k_scatlin0(
    const int* __restrict__ src, const int* __restrict__ dst,
    const int* __restrict__ indptr, int* __restrict__ cursor, int* __restrict__ ssrc,
    const float* __restrict__ mc, const float* __restrict__ speeds,
    const float* __restrict__ dist, const float* __restrict__ ttg,
    const int* __restrict__ mask,
    const float* __restrict__ Wq0, const float* __restrict__ bq0,
    const float* __restrict__ Wk0, const float* __restrict__ bk0,
    const float* __restrict__ Wv0, const float* __restrict__ bv0,
    const float* __restrict__ Ws0, const float* __restrict__ bs0,
    ushort* __restrict__ Y, unsigned char* __restrict__ KV)
{
    if (blockIdx.x < 512) {            // scatter
        int e = blockIdx.x * 256 + threadIdx.x;
        int d = dst[e];
        int p = atomicAdd(&cursor[d], 1);
        ssrc[indptr[d] + p] = src[e];
        return;
    }
    int n = blockIdx.x - 512;          // lin0, node n
    int u = n >> 9, m = n & 511;
    float x[6];
    x[0] = mc[m * 2 + 0];
    x[1] = mc[m * 2 + 1];
    x[2] = (float)mask[u * MM + m];
    x[3] = speeds[u];
    x[4] = dist[u * MM + m];
    x[5] = ttg[u * MM + m];

    int j = threadIdx.x;               // cols j*8..j*8+7 of 2048
    int col0 = j * 8;
    int which = col0 >> 9, jj = col0 & 511;
    const float* W = which == 0 ? Wq0 : which == 1 ? Wk0 : which == 2 ? Wv0 : Ws0;
    const float* b = which == 0 ? bq0 : which == 1 ? bk0 : which == 2 ? bv0 : bs0;
    float s[8];
#pragma unroll
    for (int uu = 0; uu < 8; ++uu) s[uu] = b[jj + uu];
#pragma unroll
    for (int t = 0; t < 6; ++t)
#pragma unroll
        for (int uu = 0; uu < 8; ++uu)
            s[uu] = fmaf(x[t], W[t * HID + jj + uu], s[uu]);
    if (which == 0 || which == 3) {            // q -> Y[0..511], s -> Y[512..1023]
        bf16x8 o8;
#pragma unroll
        for (int uu = 0; uu < 8; ++uu) o8[uu] = (short)f2bf(s[uu]);
        *(bf16x8*)(Y + (size_t)n * NQS + (which == 0 ? jj : 512 + jj)) = o8;
    } else if (which == 2) {                   // v -> KV (bf16)
        bf16x8 o8;
#pragma unroll
        for (int uu = 0; uu < 8; ++uu) o8[uu] = (short)f2bf(s[uu]);
        *(bf16x8*)(KV + (size_t)n * KVREC + KOFF_V + jj * 2) = o8;
    } else {                                   // k -> KV
#if HAVE_FP8
        int w0 = __builtin_amdgcn_cvt_pk_fp8_f32(s[0] * KSCALE, s[1] * KSCALE, 0, false);
        w0     = __builtin_amdgcn_cvt_pk_fp8_f32(s[2] * KSCALE, s[3] * KSCALE, w0, true);
        int w1 = __builtin_amdgcn_cvt_pk_fp8_f32(s[4] * KSCALE, s[5] * KSCALE, 0, false);
        w1     = __builtin_amdgcn_cvt_pk_fp8_f32(s[6] * KSCALE, s[7] * KSCALE, w1, true);
        uint2 uu2; uu2.x = (unsigned)w0; uu2.y = (unsigned)w1;
        *(uint2*)(KV + (size_t)n * KVREC + jj) = uu2;
#else
        bf16x8 o8;
#pragma unroll
        for (int uu = 0; uu < 8; ++uu) o8[uu] = (short)f2bf(s[uu]);
        *(bf16x8*)(KV + (size_t)n * KVREC + jj * 2) = o8;
#endif
    }
}

// ------- bf16 MFMA GEMM (r4/r8 proven structure): X @ Wt^T + bias -> Y(q,s)/KV(k,v) -------
#define GBM 128
#define GBN 128
#define GBK 64
#define TILEB (GBM * GBK * 2)   // 16384 B per matrix tile
#define BUFB  (2 * TILEB)       // 32768 B per buffer (A+B)

__device__ __forceinline__ void stage_tile(
    const ushort* __restrict__ Ag, const ushort* __restrict__ Bg,
    char* __restrict__ base, int t)
{
    const int lane = t & 63;
    const int w = t >> 6;           // wave 0..3
    const int r8 = lane >> 3;       // row within 8-row slab
    const int c  = lane & 7;        // col16 slot
    const int csw = c ^ r8;         // XOR-swizzled source col
#pragma unroll
    for (int i = 0; i < 4; ++i) {
        int r0 = (w * 4 + i) * 8;   // 0,8,...,120
        __builtin_amdgcn_global_load_lds(
            (const __attribute__((address_space(1))) void*)(Ag + (size_t)(r0 + r8) * HID + csw * 8),
            (__attribute__((address_space(3))) void*)(base + r0 * 128 + lane * 16), 16, 0, 0);
        __builtin_amdgcn_global_load_lds(
            (const __attribute__((address_space(1))) void*)(Bg + (size_t)(r0 + r8) * HID + csw * 8),
            (__attribute__((address_space(3))) void*)(base + TILEB + r0 * 128 + lane * 16), 16, 0, 0);
    }
}

__global__ __launch_bounds__(256, 2) void k_gemm(
    const ushort* __restrict__ A,    // [8192][512] bf16
    const ushort* __restrict__ Bt,   // [2048][512] bf16 (weights, [n][k])
    const float* __restrict__ bias,  // [2048] fp32
    ushort* __restrict__ Y,          // [8192][1024] bf16 (q|s)
    unsigned char* __restrict__ KV)  // [8192][KVREC] packed k+v
{
    __shared__ char lds[2 * BUFB];   // 65536 B
    const int t = threadIdx.x;
    // bijective XCD remap (1024 blocks, 8 XCDs, m-band per XCD)
    const int bid = blockIdx.x;
    const int xcd = bid & 7;
    const int ii  = bid >> 3;                 // 0..127
    const int mi  = (xcd << 3) | (ii & 7);    // 0..63
    const int ni  = ii >> 3;                  // 0..15
    const int m0 = mi * GBM, n0 = ni * GBN;

    const int wid = t >> 6, lane = t & 63;
    const int wr = wid >> 1, wc = wid & 1;    // 2x2 waves, 64x64 out each
    const int l15 = lane & 15, lkq = lane >> 4;

    f32x4 acc[4][4] = {};

    const ushort* Ab = A + (size_t)m0 * HID;
    const ushort* Bb = Bt + (size_t)n0 * HID;

    stage_tile(Ab, Bb, lds, t);
    int cur = 0;
    const int NKS = HID / GBK;   // 8
    for (int T = 0; T < NKS; ++T) {
        __syncthreads();         // drains stage of buf[cur]; protects buf[cur^1] rewrite
        if (T + 1 < NKS)
            stage_tile(Ab + (T + 1) * GBK, Bb + (T + 1) * GBK,
                       lds + (cur ^ 1) * BUFB, t);
        const char* la = lds + cur * BUFB;
        const char* lb = la + TILEB;
#pragma unroll
        for (int kh = 0; kh < 2; ++kh) {
            const int kq = kh * 4 + lkq;
            const int sw = (kq ^ (l15 & 7)) << 4;
            bf16x8 a[4], b[4];
#pragma unroll
            for (int i = 0; i < 4; ++i)
                a[i] = *(const bf16x8*)(la + (wr * 64 + i * 16 + l15) * 128 + sw);
#pragma unroll
            for (int j = 0; j < 4; ++j)
                b[j] = *(const bf16x8*)(lb + (wc * 64 + j * 16 + l15) * 128 + sw);
#pragma unroll
            for (int i = 0; i < 4; ++i)
#pragma unroll
                for (int j = 0; j < 4; ++j)
                    acc[i][j] = __builtin_amdgcn_mfma_f32_16x16x32_bf16(a[i], b[j], acc[i][j], 0, 0, 0);
        }
        cur ^= 1;
    }

    const int whichq = n0 >> 9;   // 0=q 1=k 2=v 3=s (128-tile never straddles quarters)
    // epilogue: C/D layout col=lane&15, row=(lane>>4)*4+reg
#pragma unroll
    for (int i = 0; i < 4; ++i) {
        int row = m0 + wr * 64 + i * 16 + lkq * 4;
#pragma unroll
        for (int j = 0; j < 4; ++j) {
            int col = n0 + wc * 64 + j * 16 + l15;
            float bc = bias[col];
            f32x4 r = acc[i][j];
#pragma unroll
            for (int g = 0; g < 4; ++g) {
                float val = r[g] + bc;
                if (whichq == 0) {
                    Y[(size_t)(row + g) * NQS + col] = f2bf(val);
                } else if (whichq == 3) {
                    Y[(size_t)(row + g) * NQS + (col - 1024)] = f2bf(val);
                } else if (whichq == 2) {          // v -> KV bf16
                    *(ushort*)(KV + (size_t)(row + g) * KVREC + KOFF_V + (col - 1024) * 2) = f2bf(val);
                } else {                            // k -> KV
#if HAVE_FP8
                    int pk = __builtin_amdgcn_cvt_pk_fp8_f32(val * KSCALE, val * KSCALE, 0, false);
                    KV[(size_t)(row + g) * KVREC + (col - 512)] = (unsigned char)(pk & 0xff);
#else
                    *(ushort*)(KV + (size_t)(row + g) * KVREC + (col - 512) * 2) = f2bf(val);
#endif
                }
            }
        }
    }
}

// ------- per-node attention (1 wave/node, 4 nodes/block), 2-deep prefetch -------
// last!=0: skip X write; block-pool the 4 nodes -> xsumP128[u][pblk][512]
__global__ __launch_bounds__(256) void k_attn(
    const int* __restrict__ indptr, const int* __restrict__ ssrc,
    const ushort* __restrict__ Y,          // [N][1024] q|s
    const unsigned char* __restrict__ KV,  // [N][KVREC]
    ushort* __restrict__ X,                // [N][512] bf16 out (layers 0..2)
    float* __restrict__ xsumP128,          // [16][128][512] partials (last layer)
    int last)
{
    __shared__ float pbuf[4][512];
    int n = blockIdx.x * 4 + (threadIdx.x >> 6);
    int wv = threadIdx.x >> 6;
    int l = threadIdx.x & 63;
    int cbase = l * 8;
    const ushort* yq = Y + (size_t)n * NQS + cbase;
    float qf[8];
    {
        bf16x8 q8 = *(const bf16x8*)yq;
#pragma unroll
        for (int j = 0; j < 8; ++j) qf[j] = bf2f((ushort)q8[j]);
    }
    float mrun = -INFINITY, ssum = 0.f;
    float acc[8] = {};
    int e0 = indptr[n], e1 = indptr[n + 1];
#if HAVE_FP8
    uint2 ka = {}, kb = {};
#define KLOAD(K_, base_) K_ = *(const uint2*)((base_) + cbase)
#else
    bf16x8 ka = {}, kb = {};
#define KLOAD(K_, base_) K_ = *(const bf16x8*)((base_) + cbase * 2)
#endif
    bf16x8 va = {}, vb = {};
    if (e0 < e1) {
        const unsigned char* r = KV + (size_t)ssrc[e0] * KVREC;
        KLOAD(ka, r);
        va = *(const bf16x8*)(r + KOFF_V + cbase * 2);
    }
    if (e0 + 1 < e1) {
        const unsigned char* r = KV + (size_t)ssrc[e0 + 1] * KVREC;
        KLOAD(kb, r);
        vb = *(const bf16x8*)(r + KOFF_V + cbase * 2);
    }
    for (int e = e0; e < e1; ++e) {
        auto k8 = ka; bf16x8 v8 = va;
        ka = kb; va = vb;
        int en = e + 2;
        if (en < e1) {
            const unsigned char* r = KV + (size_t)ssrc[en] * KVREC;
            KLOAD(kb, r);
            vb = *(const bf16x8*)(r + KOFF_V + cbase * 2);
        }
        float part = 0.f;
#if HAVE_FP8
        {
            f32x2 k01 = __builtin_amdgcn_cvt_pk_f32_fp8((int)k8.x, false);
            f32x2 k23 = __builtin_amdgcn_cvt_pk_f32_fp8((int)k8.x, true);
            f32x2 k45 = __builtin_amdgcn_cvt_pk_f32_fp8((int)k8.y, false);
            f32x2 k67 = __builtin_amdgcn_cvt_pk_f32_fp8((int)k8.y, true);
            part = fmaf(qf[0], k01.x, part); part = fmaf(qf[1], k01.y, part);
            part = fmaf(qf[2], k23.x, part); part = fmaf(qf[3], k23.y, part);
            part = fmaf(qf[4], k45.x, part); part = fmaf(qf[5], k45.y, part);
            part = fmaf(qf[6], k67.x, part); part = fmaf(qf[7], k67.y, part);
        }
        const float smul = KISCALE;
#else
#pragma unroll
        for (int j = 0; j < 8; ++j) part = fmaf(qf[j], bf2f((ushort)k8[j]), part);
        const float smul = 0.125f;
#endif
        part += __shfl_xor(part, 1);
        part += __shfl_xor(part, 2);
        part += __shfl_xor(part, 4);
        float score = part * smul;
        float mnew = fmaxf(mrun, score);
        float sc = __expf(mrun - mnew);
        float p = __expf(score - mnew);
        ssum = ssum * sc + p;
#pragma unroll
        for (int j = 0; j < 8; ++j)
            acc[j] = fmaf(acc[j], sc, p * bf2f((ushort)v8[j]));
        mrun = mnew;
    }
    float inv = ssum > 0.f ? 1.f / ssum : 0.f;
    float o[8];
#pragma unroll
    for (int j = 0; j < 8; ++j)
        o[j] = fmaxf(fmaf(acc[j], inv, bf2f(yq[512 + j])), 0.f);  // + skip, ReLU

    if (!last) {
        bf16x8 o8;
#pragma unroll
        for (int j = 0; j < 8; ++j) o8[j] = (short)f2bf(o[j]);
        *(bf16x8*)(X + (size_t)n * HID + cbase) = o8;
        return;
    }
    // last layer: pool the block's 4 nodes (same u, same 4-node partition)
#pragma unroll
    for (int j = 0; j < 8; ++j) pbuf[wv][cbase + j] = o[j];
    __syncthreads();
    int n0 = blockIdx.x * 4;
    int u = n0 >> 9, pblk = (n0 & 511) >> 2;    // 0..127
    float* dstp = xsumP128 + ((size_t)u * 128 + pblk) * 512;
#pragma unroll
    for (int rep = 0; rep < 2; ++rep) {
        int c = rep * 256 + threadIdx.x;
        dstp[c] = pbuf[0][c] + pbuf[1][c] + pbuf[2][c] + pbuf[3][c];
    }
}

// ------- fused: reduce partials, emb = xsum @ Wout + M*bout, actor/critic head -------
__global__ __launch_bounds__(512) void k_embhead(
    const float* __restrict__ xsumP128, const float* __restrict__ Wout,
    const float* __restrict__ bout,
    const float* __restrict__ uavs, const float* __restrict__ speeds,
    const float* __restrict__ Wc1, const float* __restrict__ bc1,
    const float* __restrict__ Wc2, const float* __restrict__ bc2,
    float* __restrict__ out)
{
    __shared__ float xs[HID];
    __shared__ float comb[67];
    __shared__ float red[128];
    int u = blockIdx.x, c = threadIdx.x;
    const float* base = xsumP128 + (size_t)u * 128 * 512 + c;
    float s = 0.f;
    for (int p = 0; p < 128; ++p) s += base[p * 512];
    xs[c] = s;
    __syncthreads();
    if (c < 64) {
        float a = 0.f;
        for (int i = 0; i < HID; ++i) a = fmaf(xs[i], Wout[i * 64 + c], a);
        comb[2 + c] = a + 512.0f * bout[c];
    }
    if (c == 64) { comb[0] = uavs[u * 2]; comb[1] = uavs[u * 2 + 1]; }
    if (c == 65) comb[66] = speeds[u];
    __syncthreads();
    if (c < 128) {
        float a = bc1[c];
        for (int i = 0; i < 67; ++i) a = fmaf(comb[i], Wc1[i * 128 + c], a);
        a = fmaxf(a, 0.f);
        red[c] = a * Wc2[c];
    }
    __syncthreads();
    for (int sft = 64; sft > 0; sft >>= 1) {
        if (c < sft) red[c] += red[c + sft];
        __syncthreads();
    }
    if (c == 0) {
        out[u]      = 1.0f;                 // softmax over singleton axis
        out[16 + u] = red[0] + bc2[0];
    }
}

extern "C" void kernel_launch(void* const* d_in, const int* in_sizes, int n_in,
                              void* d_out, int out_size, void* d_ws, size_t ws_size,
                              hipStream_t stream)
{
    const float* mission_coords = (const float*)d_in[0];
    const float* uavs_info      = (const float*)d_in[1];
    const float* speeds         = (const float*)d_in[2];
    const float* dist_matrix    = (const float*)d_in[3];
    const float* timetogo       = (const float*)d_in[4];
    const int*   action_mask    = (const int*)d_in[5];
    const int*   edge_index     = (const int*)d_in[6];
    const float* Wq0 = (const float*)d_in[8];  const float* bq0 = (const float*)d_in[9];
    const float* Wk0 = (const float*)d_in[10]; const float* bk0 = (const float*)d_in[11];
    const float* Wv0 = (const float*)d_in[12]; const float* bv0 = (const float*)d_in[13];
    const float* Ws0 = (const float*)d_in[14]; const float* bs0 = (const float*)d_in[15];
    const float* Wq  = (const float*)d_in[16]; const float* bq  = (const float*)d_in[17];
    const float* Wk  = (const float*)d_in[18]; const float* bk  = (const float*)d_in[19];
    const float* Wv  = (const float*)d_in[20]; const float* bv  = (const float*)d_in[21];
    const float* Ws  = (const float*)d_in[22]; const float* bs  = (const float*)d_in[23];
    const float* Wout = (const float*)d_in[24]; const float* bout = (const float*)d_in[25];
    const float* Wc1 = (const float*)d_in[30]; const float* bc1 = (const float*)d_in[31];
    const float* Wc2 = (const float*)d_in[32]; const float* bc2 = (const float*)d_in[33];
    float* out = (float*)d_out;

    const int* e_src = edge_index;
    const int* e_dst = edge_index + NEDGES;

    // ---- workspace carve ----
    char* p = (char*)d_ws;
    ushort* Ybf = (ushort*)p;  p += (size_t)NNODES * NQS * 2;     // 16 MB
    ushort* Xbf = (ushort*)p;  p += (size_t)NNODES * HID * 2;     // 8 MB
    ushort* Wt  = (ushort*)p;  p += (size_t)3 * 2048 * HID * 2;   // 6 MB
    unsigned char* KV = (unsigned char*)p; p += (size_t)NNODES * KVREC;
    float* bcat = (float*)p;   p += (size_t)3 * 2048 * 4;
    float* xsumP128 = (float*)p; p += (size_t)UU * 128 * HID * 4; // 4 MB
    int* cnt    = (int*)p;     p += (size_t)NNODES * 4;           // zero region start
    int* cursor = (int*)p;     p += (size_t)NNODES * 4;
    int* done   = (int*)p;     p += (size_t)512 * 4;              // done + pad
    int* indptr = (int*)p;     p += (size_t)(NNODES + 1) * 4;
    int* ssrc   = (int*)p;     p += (size_t)NEDGES * 4;

    // ---- prep: weights+bias+zeroing (fused), CSR hist+scan (fused) ----
    k_wtb<<<dim3(8, 8, 13), 256, 0, stream>>>(Wq, Wk, Wv, Ws, bq, bk, bv, bs,
                                              Wt, bcat, cnt);
    k_histscan<<<NEDGES / 256, 256, 0, stream>>>(e_dst, cnt, indptr, done);

    // ---- scatter + layer-0 linear (fused) ----
    k_scatlin0<<<512 + NNODES, 256, 0, stream>>>(
        e_src, e_dst, indptr, cursor, ssrc,
        mission_coords, speeds, dist_matrix, timetogo, action_mask,
        Wq0, bq0, Wk0, bk0, Wv0, bv0, Ws0, bs0, Ybf, KV);
    k_attn<<<NNODES / 4, 256, 0, stream>>>(indptr, ssrc, Ybf, KV, Xbf, xsumP128, 0);

    // ---- layers 1..3: fused q|k|v|s MFMA GEMM + attention (last pools) ----
    const int ngblocks = (NNODES / GBM) * (2048 / GBN);   // 1024
    for (int l = 0; l < 3; ++l) {
        k_gemm<<<ngblocks, 256, 0, stream>>>(Xbf, Wt + (size_t)l * 2048 * HID,
                                             bcat + l * 2048, Ybf, KV);
        k_attn<<<NNODES / 4, 256, 0, stream>>>(indptr, ssrc, Ybf, KV, Xbf,
                                               xsumP128, l == 2 ? 1 : 0);
    }

    // ---- fused embedding + head ----
    k_embhead<<<UU, 512, 0, stream>>>(xsumP128, Wout, bout, uavs_info, speeds,
                                      Wc1, bc1, Wc2, bc2, out);
}

// Round 10
// 272.826 us; speedup vs baseline: 1.1190x; 1.1190x over previous
//
#include <hip/hip_runtime.h>
#include <hip/hip_bf16.h>
#include <math.h>

#define NNODES 8192
#define NEDGES 131072
#define HID    512
#define UU     16
#define MM     512
#define NQKVS  2048   // packed q|k|v|s columns (Y layout; k,v quarters unused now)
#define KVREC  1536   // per-node KV record: 512B k(fp8) + 1024B v(bf16)

#if __has_builtin(__builtin_amdgcn_cvt_pk_f32_fp8) && __has_builtin(__builtin_amdgcn_cvt_pk_fp8_f32)
#define HAVE_FP8 1
#else
#define HAVE_FP8 0
#endif

#define KSCALE 16.0f
#define KISCALE (0.125f / 16.0f)   // score = (q . 16k) * 0.125/16

typedef __attribute__((ext_vector_type(8))) short bf16x8;
typedef __attribute__((ext_vector_type(4))) float f32x4;
typedef __attribute__((ext_vector_type(2))) float f32x2;

__device__ __forceinline__ float bf2f(ushort u) {
    return __uint_as_float(((unsigned)u) << 16);
}
__device__ __forceinline__ ushort f2bf(float f) {
    unsigned x = __float_as_uint(f);
    return (ushort)((x + 0x7fffu + ((x >> 16) & 1u)) >> 16);
}

// ---------------- weight transpose+convert + bias pack + cnt zeroing (fused) ----------------
__global__ __launch_bounds__(256) void k_wtb(
    const float* __restrict__ Wq, const float* __restrict__ Wk,
    const float* __restrict__ Wv, const float* __restrict__ Ws,
    const float* __restrict__ bq, const float* __restrict__ bk,
    const float* __restrict__ bv, const float* __restrict__ bs,
    ushort* __restrict__ Wt, float* __restrict__ bcat, int* __restrict__ zbuf)
{
    __shared__ float tile[64][65];
    int z = blockIdx.z;
    int t = threadIdx.x;
    if (z == 12) {
        int id = blockIdx.y * 8 + blockIdx.x;   // 0..63
        if (id < 24) {                          // bias pack [3][2048]
            int i = id * 256 + t;
            int l = i >> 11, j = i & 2047;
            int which = j >> 9, jj = j & 511;
            const float* b = which == 0 ? bq : which == 1 ? bk : which == 2 ? bv : bs;
            bcat[i] = b[l * HID + jj];
        } else if (id < 56) {                   // zero cnt+cursor (2*NNODES ints)
            int idx = (id - 24) * 512 + t * 2;
            zbuf[idx] = 0; zbuf[idx + 1] = 0;
        }
        return;
    }
    int l = z >> 2, which = z & 3;
    const float* src = (which == 0 ? Wq : which == 1 ? Wk : which == 2 ? Wv : Ws)
                       + (size_t)l * HID * HID;
    int k0 = blockIdx.x * 64, c0 = blockIdx.y * 64;
#pragma unroll
    for (int i = 0; i < 16; ++i) {
        int idx = i * 256 + t;
        int r = idx >> 6, c = idx & 63;
        tile[r][c] = src[(size_t)(k0 + r) * HID + c0 + c];
    }
    __syncthreads();
    ushort* dst = Wt + ((size_t)l * NQKVS + which * HID + c0) * HID + k0;
#pragma unroll
    for (int i = 0; i < 16; ++i) {
        int idx = i * 256 + t;
        int r = idx >> 6, c = idx & 63;
        dst[(size_t)r * HID + c] = f2bf(tile[c][r]);
    }
}

// ---------------- layer-0 linear (in=6) with fused feature build ----------------
__global__ __launch_bounds__(256) void k_lin0(
    const float* __restrict__ mc, const float* __restrict__ speeds,
    const float* __restrict__ dist, const float* __restrict__ ttg,
    const int* __restrict__ mask,
    const float* __restrict__ Wq0, const float* __restrict__ bq0,
    const float* __restrict__ Wk0, const float* __restrict__ bk0,
    const float* __restrict__ Wv0, const float* __restrict__ bv0,
    const float* __restrict__ Ws0, const float* __restrict__ bs0,
    ushort* __restrict__ Y, unsigned char* __restrict__ KV)
{
    int n = blockIdx.x;                // node
    int u = n >> 9, m = n & 511;
    float x[6];
    x[0] = mc[m * 2 + 0];
    x[1] = mc[m * 2 + 1];
    x[2] = (float)mask[u * MM + m];
    x[3] = speeds[u];
    x[4] = dist[u * MM + m];
    x[5] = ttg[u * MM + m];

    int j = threadIdx.x;               // 0..255 -> cols j*8..j*8+7
    int col0 = j * 8;
    int which = col0 >> 9, jj = col0 & 511;
    const float* W = which == 0 ? Wq0 : which == 1 ? Wk0 : which == 2 ? Wv0 : Ws0;
    const float* b = which == 0 ? bq0 : which == 1 ? bk0 : which == 2 ? bv0 : bs0;
    float s[8];
#pragma unroll
    for (int uu = 0; uu < 8; ++uu) s[uu] = b[jj + uu];
#pragma unroll
    for (int t = 0; t < 6; ++t)
#pragma unroll
        for (int uu = 0; uu < 8; ++uu)
            s[uu] = fmaf(x[t], W[t * HID + jj + uu], s[uu]);
    if (which == 0 || which == 3) {            // q, skip -> Y
        bf16x8 o8;
#pragma unroll
        for (int uu = 0; uu < 8; ++uu) o8[uu] = (short)f2bf(s[uu]);
        *(bf16x8*)(Y + (size_t)n * NQKVS + col0) = o8;
    } else if (which == 2) {                   // v -> KV (bf16)
        bf16x8 o8;
#pragma unroll
        for (int uu = 0; uu < 8; ++uu) o8[uu] = (short)f2bf(s[uu]);
        *(bf16x8*)(KV + (size_t)n * KVREC + 512 + jj * 2) = o8;
    } else {                                   // k -> KV (fp8, scaled)
#if HAVE_FP8
        int w0 = __builtin_amdgcn_cvt_pk_fp8_f32(s[0] * KSCALE, s[1] * KSCALE, 0, false);
        w0     = __builtin_amdgcn_cvt_pk_fp8_f32(s[2] * KSCALE, s[3] * KSCALE, w0, true);
        int w1 = __builtin_amdgcn_cvt_pk_fp8_f32(s[4] * KSCALE, s[5] * KSCALE, 0, false);
        w1     = __builtin_amdgcn_cvt_pk_fp8_f32(s[6] * KSCALE, s[7] * KSCALE, w1, true);
        uint2 uu2; uu2.x = (unsigned)w0; uu2.y = (unsigned)w1;
        *(uint2*)(KV + (size_t)n * KVREC + jj) = uu2;
#else
        bf16x8 o8;
#pragma unroll
        for (int uu = 0; uu < 8; ++uu) o8[uu] = (short)f2bf(s[uu]);
        *(bf16x8*)(KV + (size_t)n * KVREC + jj * 2) = o8;
#endif
    }
}

// ---------------- bf16 MFMA GEMM, 8-phase-style counted-vmcnt pipeline ----------------
// BM=256, BN=128, BK=64. 8 waves (4M x 2N), per-wave out 64x64 (4x4 frags 16x16x32).
// LDS: 3 slots x (A 32KB + B 16KB) = 144 KB -> stage(X+2) issued during tile X,
// end-of-tile wait = vmcnt(6) (tile X+2's 6 loads stay in flight; never drain to 0
// until the tail). Per tile 2 phases: {issue 3 gloads; ds_read 8xb128; 16 MFMA; bar}.
// Same K-chunk order + XOR swizzle as round-8 kernel -> bitwise-identical result.
#define GBM 256
#define GBN 128
#define GBK 64
#define ATILE 32768             // 256 rows x 128 B
#define BTILE 16384             // 128 rows x 128 B
#define SLOTB (ATILE + BTILE)   // 49152
#define NTILES 8

#define VMCNT(n) asm volatile("s_waitcnt vmcnt(" #n ")" ::: "memory")

__device__ __forceinline__ void stage_unit(
    const ushort* __restrict__ Ag, const ushort* __restrict__ Bg,
    char* __restrict__ buf, int t, int u)
{
    int slot = u * 512 + t;
    if (slot < 2048) {                 // A: 256 rows x 8 chunks of 16B
        int row = slot >> 3, c = slot & 7;
        int csw = c ^ (row & 7);
        __builtin_amdgcn_global_load_lds(
            (const __attribute__((address_space(1))) void*)(Ag + (size_t)row * HID + csw * 8),
            (__attribute__((address_space(3))) void*)(buf + slot * 16), 16, 0, 0);
    } else {                           // B: 128 rows x 8 chunks
        int s2 = slot - 2048;
        int row = s2 >> 3, c = s2 & 7;
        int csw = c ^ (row & 7);
        __builtin_amdgcn_global_load_lds(
            (const __attribute__((address_space(1))) void*)(Bg + (size_t)row * HID + csw * 8),
            (__attribute__((address_space(3))) void*)(buf + ATILE + s2 * 16), 16, 0, 0);
    }
}

__global__ __launch_bounds__(512, 1) void k_gemm(
    const ushort* __restrict__ A,    // [8192][512] bf16
    const ushort* __restrict__ Bt,   // [2048][512] bf16 (weights, [n][k])
    const float* __restrict__ bias,  // [2048] fp32
    ushort* __restrict__ Y,          // [8192][2048] bf16 (q,s quarters)
    unsigned char* __restrict__ KV)  // [8192][1536] packed k(fp8)+v(bf16)
{
    extern __shared__ char lds[];    // 3 * SLOTB = 147456
    const int t = threadIdx.x;
    // bijective XCD remap: 512 blocks -> 8 XCDs x (4 m-tiles x 16 n-tiles)
    const int bid = blockIdx.x;
    const int xcd = bid & 7;
    const int ii  = bid >> 3;                 // 0..63
    const int mi  = (xcd << 2) | (ii & 3);    // 0..31
    const int ni  = ii >> 2;                  // 0..15
    const int m0 = mi * GBM, n0 = ni * GBN;

    const int wid = t >> 6, lane = t & 63;
    const int wr = wid >> 1, wc = wid & 1;    // 4M x 2N waves, 64x64 out each
    const int l15 = lane & 15, lkq = lane >> 4;

    f32x4 acc[4][4] = {};

    const ushort* Ab = A + (size_t)m0 * HID;
    const ushort* Bb = Bt + (size_t)n0 * HID;

    // prologue: stage tiles 0 and 1 (12 loads/thread in flight)
#pragma unroll
    for (int u = 0; u < 6; ++u) stage_unit(Ab, Bb, lds, t, u);
#pragma unroll
    for (int u = 0; u < 6; ++u) stage_unit(Ab + GBK, Bb + GBK, lds + SLOTB, t, u);
    VMCNT(6);                        // tile 0 landed; tile 1's 6 still in flight
    __builtin_amdgcn_s_barrier();
    __builtin_amdgcn_sched_barrier(0);

    const int arow = wr * 64;        // wave's A row block
    const int brow = wc * 64;        // wave's B row block
#pragma unroll
    for (int T = 0; T < NTILES; ++T) {
        char* cbuf = lds + (T % 3) * SLOTB;
        char* sbuf = lds + ((T + 2) % 3) * SLOTB;
        const ushort* An = Ab + (T + 2) * GBK;
        const ushort* Bn = Bb + (T + 2) * GBK;
#pragma unroll
        for (int ph = 0; ph < 2; ++ph) {
            if (T + 2 < NTILES) {
                stage_unit(An, Bn, sbuf, t, ph * 3 + 0);
                stage_unit(An, Bn, sbuf, t, ph * 3 + 1);
                stage_unit(An, Bn, sbuf, t, ph * 3 + 2);
            }
            __builtin_amdgcn_sched_barrier(0);
            bf16x8 a[4], b[4];
#pragma unroll
            for (int i = 0; i < 4; ++i) {
                int row = arow + i * 16 + l15;
                int kq = ph * 4 + lkq;
                a[i] = *(const bf16x8*)(cbuf + row * 128 + ((kq ^ (row & 7)) << 4));
            }
#pragma unroll
            for (int j = 0; j < 4; ++j) {
                int row = brow + j * 16 + l15;
                int kq = ph * 4 + lkq;
                b[j] = *(const bf16x8*)(cbuf + ATILE + row * 128 + ((kq ^ (row & 7)) << 4));
            }
            __builtin_amdgcn_s_setprio(1);
#pragma unroll
            for (int i = 0; i < 4; ++i)
#pragma unroll
                for (int j = 0; j < 4; ++j)
                    acc[i][j] = __builtin_amdgcn_mfma_f32_16x16x32_bf16(a[i], b[j], acc[i][j], 0, 0, 0);
            __builtin_amdgcn_s_setprio(0);
            __builtin_amdgcn_sched_barrier(0);
            if (ph == 0) {
                __builtin_amdgcn_s_barrier();
                __builtin_amdgcn_sched_barrier(0);
            }
        }
        // end of tile: ensure tile T+1 staged (6 newest = tile T+2's loads)
        if (T < NTILES - 2) { VMCNT(6); }
        else if (T == NTILES - 2) { VMCNT(0); }
        __builtin_amdgcn_s_barrier();
        __builtin_amdgcn_sched_barrier(0);
    }

    const int whichq = n0 >> 9;   // 0=q 1=k 2=v 3=s (128-tile never straddles quarters)
    // epilogue: C/D layout col=lane&15, row=(lane>>4)*4+reg
#pragma unroll
    for (int i = 0; i < 4; ++i) {
        int row = m0 + arow + i * 16 + lkq * 4;
#pragma unroll
        for (int j = 0; j < 4; ++j) {
            int col = n0 + brow + j * 16 + l15;
            float bc = bias[col];
            f32x4 r = acc[i][j];
#pragma unroll
            for (int g = 0; g < 4; ++g) {
                float val = r[g] + bc;
                if (whichq == 0 || whichq == 3) {
                    Y[(size_t)(row + g) * NQKVS + col] = f2bf(val);
                } else if (whichq == 2) {          // v -> KV bf16
                    *(ushort*)(KV + (size_t)(row + g) * KVREC + 512 + (col - 1024) * 2) = f2bf(val);
                } else {                            // k -> KV fp8
#if HAVE_FP8
                    int pk = __builtin_amdgcn_cvt_pk_fp8_f32(val * KSCALE, val * KSCALE, 0, false);
                    KV[(size_t)(row + g) * KVREC + (col - 512)] = (unsigned char)(pk & 0xff);
#else
                    *(ushort*)(KV + (size_t)(row + g) * KVREC + (col - 512) * 2) = f2bf(val);
#endif
                }
            }
        }
    }
}

// ---------------- CSR build ----------------
__global__ __launch_bounds__(256) void k_hist(const int* __restrict__ dst, int* __restrict__ cnt)
{
    int e = blockIdx.x * blockDim.x + threadIdx.x;
    if (e < NEDGES) atomicAdd(&cnt[dst[e]], 1);
}

// parallel scan: 1024 threads, 8 elems each, wave-scan + cross-wave offsets
__global__ __launch_bounds__(1024) void k_scan(const int* __restrict__ cnt, int* __restrict__ indptr)
{
    __shared__ int wsum[16];
    __shared__ int woff[16];
    int t = threadIdx.x;
    int base = t * 8;
    int v[8];
    int s = 0;
#pragma unroll
    for (int i = 0; i < 8; ++i) { v[i] = cnt[base + i]; s += v[i]; }
    int lane = t & 63, w = t >> 6;
    int incl = s;
#pragma unroll
    for (int off = 1; off < 64; off <<= 1) {
        int u = __shfl_up(incl, off);
        if (lane >= off) incl += u;
    }
    if (lane == 63) wsum[w] = incl;
    __syncthreads();
    if (t == 0) {
        int run = 0;
#pragma unroll
        for (int i = 0; i < 16; ++i) { woff[i] = run; run += wsum[i]; }
    }
    __syncthreads();
    int run = woff[w] + incl - s;     // exclusive prefix for this chunk
#pragma unroll
    for (int i = 0; i < 8; ++i) { indptr[base + i] = run; run += v[i]; }
    if (t == 1023) indptr[NNODES] = run;
}

__global__ __launch_bounds__(256) void k_scatter(
    const int* __restrict__ src, const int* __restrict__ dst,
    const int* __restrict__ indptr, int* __restrict__ cursor, int* __restrict__ ssrc)
{
    int e = blockIdx.x * blockDim.x + threadIdx.x;
    if (e >= NEDGES) return;
    int d = dst[e];
    int p = atomicAdd(&cursor[d], 1);
    ssrc[indptr[d] + p] = src[e];
}

// ---------------- per-node attention (1 wave/node, 4 nodes/block), 2-deep prefetch ----------------
__global__ __launch_bounds__(256) void k_attn(
    const int* __restrict__ indptr, const int* __restrict__ ssrc,
    const ushort* __restrict__ Y,   // [N][2048] (q, s quarters)
    const unsigned char* __restrict__ KV,   // [N][1536]
    ushort* __restrict__ X)         // [N][512] bf16 out
{
    int n = blockIdx.x * 4 + (threadIdx.x >> 6);
    if (n >= NNODES) return;
    int l = threadIdx.x & 63;
    int cbase = l * 8;
    const ushort* yq = Y + (size_t)n * NQKVS + cbase;
    float qf[8];
    {
        bf16x8 q8 = *(const bf16x8*)yq;
#pragma unroll
        for (int j = 0; j < 8; ++j) qf[j] = bf2f((ushort)q8[j]);
    }
    float mrun = -INFINITY, ssum = 0.f;
    float acc[8] = {};
    int e0 = indptr[n], e1 = indptr[n + 1];
#if HAVE_FP8
    uint2 ka = {}, kb = {};
#define KLOAD(K_, base_) K_ = *(const uint2*)((base_) + cbase)
#else
    bf16x8 ka = {}, kb = {};
#define KLOAD(K_, base_) K_ = *(const bf16x8*)((base_) + cbase * 2)
#endif
    bf16x8 va = {}, vb = {};
    if (e0 < e1) {
        const unsigned char* r = KV + (size_t)ssrc[e0] * KVREC;
        KLOAD(ka, r);
        va = *(const bf16x8*)(r + 512 + cbase * 2);
    }
    if (e0 + 1 < e1) {
        const unsigned char* r = KV + (size_t)ssrc[e0 + 1] * KVREC;
        KLOAD(kb, r);
        vb = *(const bf16x8*)(r + 512 + cbase * 2);
    }
    for (int e = e0; e < e1; ++e) {
        auto k8 = ka; bf16x8 v8 = va;
        ka = kb; va = vb;
        int en = e + 2;
        if (en < e1) {
            const unsigned char* r = KV + (size_t)ssrc[en] * KVREC;
            KLOAD(kb, r);
            vb = *(const bf16x8*)(r + 512 + cbase * 2);
        }
        float part = 0.f;
#if HAVE_FP8
        {
            f32x2 k01 = __builtin_amdgcn_cvt_pk_f32_fp8((int)k8.x, false);
            f32x2 k23 = __builtin_amdgcn_cvt_pk_f32_fp8((int)k8.x, true);
            f32x2 k45 = __builtin_amdgcn_cvt_pk_f32_fp8((int)k8.y, false);
            f32x2 k67 = __builtin_amdgcn_cvt_pk_f32_fp8((int)k8.y, true);
            part = fmaf(qf[0], k01.x, part); part = fmaf(qf[1], k01.y, part);
            part = fmaf(qf[2], k23.x, part); part = fmaf(qf[3], k23.y, part);
            part = fmaf(qf[4], k45.x, part); part = fmaf(qf[5], k45.y, part);
            part = fmaf(qf[6], k67.x, part); part = fmaf(qf[7], k67.y, part);
        }
        const float smul = KISCALE;
#else
#pragma unroll
        for (int j = 0; j < 8; ++j) part = fmaf(qf[j], bf2f((ushort)k8[j]), part);
        const float smul = 0.125f;
#endif
        part += __shfl_xor(part, 1);
        part += __shfl_xor(part, 2);
        part += __shfl_xor(part, 4);
        float score = part * smul;
        float mnew = fmaxf(mrun, score);
        float sc = __expf(mrun - mnew);
        float p = __expf(score - mnew);
        ssum = ssum * sc + p;
#pragma unroll
        for (int j = 0; j < 8; ++j)
            acc[j] = fmaf(acc[j], sc, p * bf2f((ushort)v8[j]));
        mrun = mnew;
    }
    float inv = ssum > 0.f ? 1.f / ssum : 0.f;
    bf16x8 o8;
#pragma unroll
    for (int j = 0; j < 8; ++j) {
        float o = fmaxf(fmaf(acc[j], inv, bf2f(yq[1536 + j])), 0.f);  // + skip, ReLU
        o8[j] = (short)f2bf(o);
    }
    *(bf16x8*)(X + (size_t)n * HID + cbase) = o8;
}

// ---------------- pooling: xsumP[u][p][c] = partial sums over 64 rows ----------------
__global__ __launch_bounds__(512) void k_pool(const ushort* __restrict__ X, float* __restrict__ xsumP)
{
    int u = blockIdx.x;
    int pp = blockIdx.y;               // 0..7
    int c = threadIdx.x;
    const ushort* base = X + ((size_t)u * MM + pp * 64) * HID + c;
    float s = 0.f;
    for (int m = 0; m < 64; ++m) s += bf2f(base[(size_t)m * HID]);
    xsumP[((size_t)u * 8 + pp) * HID + c] = s;
}

// ---------------- fused: emb = xsum @ Wout + M*bout, then actor/critic head ----------------
__global__ __launch_bounds__(512) void k_embhead(
    const float* __restrict__ xsumP, const float* __restrict__ Wout,
    const float* __restrict__ bout,
    const float* __restrict__ uavs, const float* __restrict__ speeds,
    const float* __restrict__ Wc1, const float* __restrict__ bc1,
    const float* __restrict__ Wc2, const float* __restrict__ bc2,
    float* __restrict__ out)
{
    __shared__ float xs[HID];
    __shared__ float comb[67];
    __shared__ float red[128];
    int u = blockIdx.x, c = threadIdx.x;
    float s = 0.f;
#pragma unroll
    for (int p = 0; p < 8; ++p) s += xsumP[((size_t)u * 8 + p) * HID + c];
    xs[c] = s;
    __syncthreads();
    if (c < 64) {
        float a = 0.f;
        for (int i = 0; i < HID; ++i) a = fmaf(xs[i], Wout[i * 64 + c], a);
        comb[2 + c] = a + 512.0f * bout[c];
    }
    if (c == 64) { comb[0] = uavs[u * 2]; comb[1] = uavs[u * 2 + 1]; }
    if (c == 65) comb[66] = speeds[u];
    __syncthreads();
    if (c < 128) {
        float a = bc1[c];
        for (int i = 0; i < 67; ++i) a = fmaf(comb[i], Wc1[i * 128 + c], a);
        a = fmaxf(a, 0.f);
        red[c] = a * Wc2[c];
    }
    __syncthreads();
    for (int sft = 64; sft > 0; sft >>= 1) {
        if (c < sft) red[c] += red[c + sft];
        __syncthreads();
    }
    if (c == 0) {
        out[u]      = 1.0f;                 // softmax over singleton axis
        out[16 + u] = red[0] + bc2[0];
    }
}

extern "C" void kernel_launch(void* const* d_in, const int* in_sizes, int n_in,
                              void* d_out, int out_size, void* d_ws, size_t ws_size,
                              hipStream_t stream)
{
    const float* mission_coords = (const float*)d_in[0];
    const float* uavs_info      = (const float*)d_in[1];
    const float* speeds         = (const float*)d_in[2];
    const float* dist_matrix    = (const float*)d_in[3];
    const float* timetogo       = (const float*)d_in[4];
    const int*   action_mask    = (const int*)d_in[5];
    const int*   edge_index     = (const int*)d_in[6];
    const float* Wq0 = (const float*)d_in[8];  const float* bq0 = (const float*)d_in[9];
    const float* Wk0 = (const float*)d_in[10]; const float* bk0 = (const float*)d_in[11];
    const float* Wv0 = (const float*)d_in[12]; const float* bv0 = (const float*)d_in[13];
    const float* Ws0 = (const float*)d_in[14]; const float* bs0 = (const float*)d_in[15];
    const float* Wq  = (const float*)d_in[16]; const float* bq  = (const float*)d_in[17];
    const float* Wk  = (const float*)d_in[18]; const float* bk  = (const float*)d_in[19];
    const float* Wv  = (const float*)d_in[20]; const float* bv  = (const float*)d_in[21];
    const float* Ws  = (const float*)d_in[22]; const float* bs  = (const float*)d_in[23];
    const float* Wout = (const float*)d_in[24]; const float* bout = (const float*)d_in[25];
    const float* Wc1 = (const float*)d_in[30]; const float* bc1 = (const float*)d_in[31];
    const float* Wc2 = (const float*)d_in[32]; const float* bc2 = (const float*)d_in[33];
    float* out = (float*)d_out;

    const int* e_src = edge_index;
    const int* e_dst = edge_index + NEDGES;

    // ---- workspace carve ----
    char* p = (char*)d_ws;
    ushort* Ybf = (ushort*)p;  p += (size_t)NNODES * NQKVS * 2;   // 32 MB
    ushort* Xbf = (ushort*)p;  p += (size_t)NNODES * HID * 2;     // 8 MB
    ushort* Wt  = (ushort*)p;  p += (size_t)3 * NQKVS * HID * 2;  // 6 MB
    unsigned char* KV = (unsigned char*)p; p += (size_t)NNODES * KVREC; // 12 MB
    float* bcat = (float*)p;   p += (size_t)3 * NQKVS * 4;
    float* xsumP = (float*)p;  p += (size_t)UU * 8 * HID * 4;
    int* cnt    = (int*)p;     p += (size_t)NNODES * 4;           // cnt+cursor adjacent
    int* cursor = (int*)p;     p += (size_t)NNODES * 4;
    int* indptr = (int*)p;     p += (size_t)(NNODES + 1) * 4;
    int* ssrc   = (int*)p;     p += (size_t)NEDGES * 4;

    // allow 144 KiB dynamic LDS for k_gemm (first call is outside graph capture)
    static bool attr_done = false;
    if (!attr_done) {
        hipFuncSetAttribute((const void*)k_gemm,
                            hipFuncAttributeMaxDynamicSharedMemorySize, 3 * SLOTB);
        attr_done = true;
    }

    // ---- prep: weights+bias+zeroing (fused), CSR ----
    k_wtb<<<dim3(8, 8, 13), 256, 0, stream>>>(Wq, Wk, Wv, Ws, bq, bk, bv, bs,
                                              Wt, bcat, cnt);
    k_hist<<<NEDGES / 256, 256, 0, stream>>>(e_dst, cnt);
    k_scan<<<1, 1024, 0, stream>>>(cnt, indptr);
    k_scatter<<<NEDGES / 256, 256, 0, stream>>>(e_src, e_dst, indptr, cursor, ssrc);

    // ---- layer 0 (in=6, fused feature build) ----
    k_lin0<<<NNODES, 256, 0, stream>>>(mission_coords, speeds, dist_matrix, timetogo,
                                       action_mask, Wq0, bq0, Wk0, bk0, Wv0, bv0,
                                       Ws0, bs0, Ybf, KV);
    k_attn<<<NNODES / 4, 256, 0, stream>>>(indptr, ssrc, Ybf, KV, Xbf);

    // ---- layers 1..3: fused q|k|v|s MFMA GEMM (pipelined) + attention ----
    const int ngblocks = (NNODES / GBM) * (NQKVS / GBN);   // 32*16 = 512
    for (int l = 0; l < 3; ++l) {
        k_gemm<<<ngblocks, 512, 3 * SLOTB, stream>>>(Xbf, Wt + (size_t)l * NQKVS * HID,
                                                     bcat + l * NQKVS, Ybf, KV);
        k_attn<<<NNODES / 4, 256, 0, stream>>>(indptr, ssrc, Ybf, KV, Xbf);
    }

    // ---- pooling + fused embedding/head ----
    k_pool<<<dim3(UU, 8), 512, 0, stream>>>(Xbf, xsumP);
    k_embhead<<<UU, 512, 0, stream>>>(xsumP, Wout, bout, uavs_info, speeds,
                                      Wc1, bc1, Wc2, bc2, out);
}

// Round 11
// 268.187 us; speedup vs baseline: 1.1384x; 1.0173x over previous
//
#include <hip/hip_runtime.h>
#include <hip/hip_bf16.h>
#include <math.h>

#define NNODES 8192
#define NEDGES 131072
#define HID    512
#define UU     16
#define MM     512
#define NQKVS  2048   // packed q|k|v|s columns (Y layout; k,v quarters unused now)
#define KVREC  1536   // per-node KV record: 512B k(fp8) + 1024B v(bf16)

#if __has_builtin(__builtin_amdgcn_cvt_pk_f32_fp8) && __has_builtin(__builtin_amdgcn_cvt_pk_fp8_f32)
#define HAVE_FP8 1
#else
#define HAVE_FP8 0
#endif

#define KSCALE 16.0f
#define KISCALE (0.125f / 16.0f)   // score = (q . 16k) * 0.125/16

typedef __attribute__((ext_vector_type(8))) short bf16x8;
typedef __attribute__((ext_vector_type(4))) float f32x4;
typedef __attribute__((ext_vector_type(2))) float f32x2;

__device__ __forceinline__ float bf2f(ushort u) {
    return __uint_as_float(((unsigned)u) << 16);
}
__device__ __forceinline__ ushort f2bf(float f) {
    unsigned x = __float_as_uint(f);
    return (ushort)((x + 0x7fffu + ((x >> 16) & 1u)) >> 16);
}

// ---------------- weight transpose+convert + bias pack + cnt zeroing (fused) ----------------
__global__ __launch_bounds__(256) void k_wtb(
    const float* __restrict__ Wq, const float* __restrict__ Wk,
    const float* __restrict__ Wv, const float* __restrict__ Ws,
    const float* __restrict__ bq, const float* __restrict__ bk,
    const float* __restrict__ bv, const float* __restrict__ bs,
    ushort* __restrict__ Wt, float* __restrict__ bcat, int* __restrict__ zbuf)
{
    __shared__ float tile[64][65];
    int z = blockIdx.z;
    int t = threadIdx.x;
    if (z == 12) {
        int id = blockIdx.y * 8 + blockIdx.x;   // 0..63
        if (id < 24) {                          // bias pack [3][2048]
            int i = id * 256 + t;
            int l = i >> 11, j = i & 2047;
            int which = j >> 9, jj = j & 511;
            const float* b = which == 0 ? bq : which == 1 ? bk : which == 2 ? bv : bs;
            bcat[i] = b[l * HID + jj];
        } else if (id < 56) {                   // zero cnt+cursor (2*NNODES ints)
            int idx = (id - 24) * 512 + t * 2;
            zbuf[idx] = 0; zbuf[idx + 1] = 0;
        }
        return;
    }
    int l = z >> 2, which = z & 3;
    const float* src = (which == 0 ? Wq : which == 1 ? Wk : which == 2 ? Wv : Ws)
                       + (size_t)l * HID * HID;
    int k0 = blockIdx.x * 64, c0 = blockIdx.y * 64;
#pragma unroll
    for (int i = 0; i < 16; ++i) {
        int idx = i * 256 + t;
        int r = idx >> 6, c = idx & 63;
        tile[r][c] = src[(size_t)(k0 + r) * HID + c0 + c];
    }
    __syncthreads();
    ushort* dst = Wt + ((size_t)l * NQKVS + which * HID + c0) * HID + k0;
#pragma unroll
    for (int i = 0; i < 16; ++i) {
        int idx = i * 256 + t;
        int r = idx >> 6, c = idx & 63;
        dst[(size_t)r * HID + c] = f2bf(tile[c][r]);
    }
}

// ---------------- layer-0 linear (in=6) with fused feature build ----------------
__global__ __launch_bounds__(256) void k_lin0(
    const float* __restrict__ mc, const float* __restrict__ speeds,
    const float* __restrict__ dist, const float* __restrict__ ttg,
    const int* __restrict__ mask,
    const float* __restrict__ Wq0, const float* __restrict__ bq0,
    const float* __restrict__ Wk0, const float* __restrict__ bk0,
    const float* __restrict__ Wv0, const float* __restrict__ bv0,
    const float* __restrict__ Ws0, const float* __restrict__ bs0,
    ushort* __restrict__ Y, unsigned char* __restrict__ KV)
{
    int n = blockIdx.x;                // node
    int u = n >> 9, m = n & 511;
    float x[6];
    x[0] = mc[m * 2 + 0];
    x[1] = mc[m * 2 + 1];
    x[2] = (float)mask[u * MM + m];
    x[3] = speeds[u];
    x[4] = dist[u * MM + m];
    x[5] = ttg[u * MM + m];

    int j = threadIdx.x;               // 0..255 -> cols j*8..j*8+7
    int col0 = j * 8;
    int which = col0 >> 9, jj = col0 & 511;
    const float* W = which == 0 ? Wq0 : which == 1 ? Wk0 : which == 2 ? Wv0 : Ws0;
    const float* b = which == 0 ? bq0 : which == 1 ? bk0 : which == 2 ? bv0 : bs0;
    float s[8];
#pragma unroll
    for (int uu = 0; uu < 8; ++uu) s[uu] = b[jj + uu];
#pragma unroll
    for (int t = 0; t < 6; ++t)
#pragma unroll
        for (int uu = 0; uu < 8; ++uu)
            s[uu] = fmaf(x[t], W[t * HID + jj + uu], s[uu]);
    if (which == 0 || which == 3) {            // q, skip -> Y
        bf16x8 o8;
#pragma unroll
        for (int uu = 0; uu < 8; ++uu) o8[uu] = (short)f2bf(s[uu]);
        *(bf16x8*)(Y + (size_t)n * NQKVS + col0) = o8;
    } else if (which == 2) {                   // v -> KV (bf16)
        bf16x8 o8;
#pragma unroll
        for (int uu = 0; uu < 8; ++uu) o8[uu] = (short)f2bf(s[uu]);
        *(bf16x8*)(KV + (size_t)n * KVREC + 512 + jj * 2) = o8;
    } else {                                   // k -> KV (fp8, scaled)
#if HAVE_FP8
        int w0 = __builtin_amdgcn_cvt_pk_fp8_f32(s[0] * KSCALE, s[1] * KSCALE, 0, false);
        w0     = __builtin_amdgcn_cvt_pk_fp8_f32(s[2] * KSCALE, s[3] * KSCALE, w0, true);
        int w1 = __builtin_amdgcn_cvt_pk_fp8_f32(s[4] * KSCALE, s[5] * KSCALE, 0, false);
        w1     = __builtin_amdgcn_cvt_pk_fp8_f32(s[6] * KSCALE, s[7] * KSCALE, w1, true);
        uint2 uu2; uu2.x = (unsigned)w0; uu2.y = (unsigned)w1;
        *(uint2*)(KV + (size_t)n * KVREC + jj) = uu2;
#else
        bf16x8 o8;
#pragma unroll
        for (int uu = 0; uu < 8; ++uu) o8[uu] = (short)f2bf(s[uu]);
        *(bf16x8*)(KV + (size_t)n * KVREC + jj * 2) = o8;
#endif
    }
}

// ---------------- bf16 MFMA GEMM (r4/r8 proven structure): X @ Wt^T + bias -> Y(q,s)/KV(k,v) ----------------
// 128x128 tile, BK=64, 4 waves (2x2), 64KB LDS double-buffered -> 2 blocks/CU.
// Staging: each gload_lds covers 8 rows x 128B contiguous (full cachelines).
// XOR swizzle (kq ^ row&7) on global SOURCE addr + ds_read index (rule #21).
#define GBM 128
#define GBN 128
#define GBK 64
#define TILEB (GBM * GBK * 2)   // 16384 B per matrix tile
#define BUFB  (2 * TILEB)       // 32768 B per buffer (A+B)

__device__ __forceinline__ void stage_tile(
    const ushort* __restrict__ Ag, const ushort* __restrict__ Bg,
    char* __restrict__ base, int t)
{
    const int lane = t & 63;
    const int w = t >> 6;           // wave 0..3
    const int r8 = lane >> 3;       // row within 8-row slab
    const int c  = lane & 7;        // col16 slot
    const int csw = c ^ r8;         // XOR-swizzled source col
#pragma unroll
    for (int i = 0; i < 4; ++i) {
        int r0 = (w * 4 + i) * 8;   // 0,8,...,120
        __builtin_amdgcn_global_load_lds(
            (const __attribute__((address_space(1))) void*)(Ag + (size_t)(r0 + r8) * HID + csw * 8),
            (__attribute__((address_space(3))) void*)(base + r0 * 128 + lane * 16), 16, 0, 0);
        __builtin_amdgcn_global_load_lds(
            (const __attribute__((address_space(1))) void*)(Bg + (size_t)(r0 + r8) * HID + csw * 8),
            (__attribute__((address_space(3))) void*)(base + TILEB + r0 * 128 + lane * 16), 16, 0, 0);
    }
}

__global__ __launch_bounds__(256, 2) void k_gemm(
    const ushort* __restrict__ A,    // [8192][512] bf16
    const ushort* __restrict__ Bt,   // [2048][512] bf16 (weights, [n][k])
    const float* __restrict__ bias,  // [2048] fp32
    ushort* __restrict__ Y,          // [8192][2048] bf16 (q,s quarters only)
    unsigned char* __restrict__ KV)  // [8192][1536] packed k(fp8)+v(bf16)
{
    __shared__ char lds[2 * BUFB];   // 65536 B
    const int t = threadIdx.x;
    // bijective XCD remap (1024 blocks, 8 XCDs, m-band per XCD)
    const int bid = blockIdx.x;
    const int xcd = bid & 7;
    const int ii  = bid >> 3;                 // 0..127
    const int mi  = (xcd << 3) | (ii & 7);    // 0..63
    const int ni  = ii >> 3;                  // 0..15
    const int m0 = mi * GBM, n0 = ni * GBN;

    const int wid = t >> 6, lane = t & 63;
    const int wr = wid >> 1, wc = wid & 1;    // 2x2 waves, 64x64 out each
    const int l15 = lane & 15, lkq = lane >> 4;

    f32x4 acc[4][4] = {};

    const ushort* Ab = A + (size_t)m0 * HID;
    const ushort* Bb = Bt + (size_t)n0 * HID;

    stage_tile(Ab, Bb, lds, t);
    int cur = 0;
    const int NKS = HID / GBK;   // 8
    for (int T = 0; T < NKS; ++T) {
        __syncthreads();         // drains stage of buf[cur]; protects buf[cur^1] rewrite
        if (T + 1 < NKS)
            stage_tile(Ab + (T + 1) * GBK, Bb + (T + 1) * GBK,
                       lds + (cur ^ 1) * BUFB, t);
        const char* la = lds + cur * BUFB;
        const char* lb = la + TILEB;
#pragma unroll
        for (int kh = 0; kh < 2; ++kh) {
            const int kq = kh * 4 + lkq;
            const int sw = (kq ^ (l15 & 7)) << 4;
            bf16x8 a[4], b[4];
#pragma unroll
            for (int i = 0; i < 4; ++i)
                a[i] = *(const bf16x8*)(la + (wr * 64 + i * 16 + l15) * 128 + sw);
#pragma unroll
            for (int j = 0; j < 4; ++j)
                b[j] = *(const bf16x8*)(lb + (wc * 64 + j * 16 + l15) * 128 + sw);
#pragma unroll
            for (int i = 0; i < 4; ++i)
#pragma unroll
                for (int j = 0; j < 4; ++j)
                    acc[i][j] = __builtin_amdgcn_mfma_f32_16x16x32_bf16(a[i], b[j], acc[i][j], 0, 0, 0);
        }
        cur ^= 1;
    }

    const int whichq = n0 >> 9;   // 0=q 1=k 2=v 3=s (128-tile never straddles quarters)
    // epilogue: C/D layout col=lane&15, row=(lane>>4)*4+reg
#pragma unroll
    for (int i = 0; i < 4; ++i) {
        int row = m0 + wr * 64 + i * 16 + lkq * 4;
#pragma unroll
        for (int j = 0; j < 4; ++j) {
            int col = n0 + wc * 64 + j * 16 + l15;
            float bc = bias[col];
            f32x4 r = acc[i][j];
#pragma unroll
            for (int g = 0; g < 4; ++g) {
                float val = r[g] + bc;
                if (whichq == 0 || whichq == 3) {
                    Y[(size_t)(row + g) * NQKVS + col] = f2bf(val);
                } else if (whichq == 2) {          // v -> KV bf16
                    *(ushort*)(KV + (size_t)(row + g) * KVREC + 512 + (col - 1024) * 2) = f2bf(val);
                } else {                            // k -> KV fp8
#if HAVE_FP8
                    int pk = __builtin_amdgcn_cvt_pk_fp8_f32(val * KSCALE, val * KSCALE, 0, false);
                    KV[(size_t)(row + g) * KVREC + (col - 512)] = (unsigned char)(pk & 0xff);
#else
                    *(ushort*)(KV + (size_t)(row + g) * KVREC + (col - 512) * 2) = f2bf(val);
#endif
                }
            }
        }
    }
}

// ---------------- CSR build ----------------
__global__ __launch_bounds__(256) void k_hist(const int* __restrict__ dst, int* __restrict__ cnt)
{
    int e = blockIdx.x * blockDim.x + threadIdx.x;
    if (e < NEDGES) atomicAdd(&cnt[dst[e]], 1);
}

// parallel scan: 1024 threads, 8 elems each, wave-scan + cross-wave offsets
__global__ __launch_bounds__(1024) void k_scan(const int* __restrict__ cnt, int* __restrict__ indptr)
{
    __shared__ int wsum[16];
    __shared__ int woff[16];
    int t = threadIdx.x;
    int base = t * 8;
    int v[8];
    int s = 0;
#pragma unroll
    for (int i = 0; i < 8; ++i) { v[i] = cnt[base + i]; s += v[i]; }
    int lane = t & 63, w = t >> 6;
    int incl = s;
#pragma unroll
    for (int off = 1; off < 64; off <<= 1) {
        int u = __shfl_up(incl, off);
        if (lane >= off) incl += u;
    }
    if (lane == 63) wsum[w] = incl;
    __syncthreads();
    if (t == 0) {
        int run = 0;
#pragma unroll
        for (int i = 0; i < 16; ++i) { woff[i] = run; run += wsum[i]; }
    }
    __syncthreads();
    int run = woff[w] + incl - s;     // exclusive prefix for this chunk
#pragma unroll
    for (int i = 0; i < 8; ++i) { indptr[base + i] = run; run += v[i]; }
    if (t == 1023) indptr[NNODES] = run;
}

__global__ __launch_bounds__(256) void k_scatter(
    const int* __restrict__ src, const int* __restrict__ dst,
    const int* __restrict__ indptr, int* __restrict__ cursor, int* __restrict__ ssrc)
{
    int e = blockIdx.x * blockDim.x + threadIdx.x;
    if (e >= NEDGES) return;
    int d = dst[e];
    int p = atomicAdd(&cursor[d], 1);
    ssrc[indptr[d] + p] = src[e];
}

// ---------------- per-node attention (1 wave/node, 4 nodes/block), 2-deep prefetch ----------------
// lane l handles channels [l*8, l*8+8); heads are 8-lane groups (shfl_xor 1,2,4).
// k (fp8) and v (bf16) from the packed per-node KV record (one 1.5KB contiguous run).
__global__ __launch_bounds__(256) void k_attn(
    const int* __restrict__ indptr, const int* __restrict__ ssrc,
    const ushort* __restrict__ Y,   // [N][2048] (q, s quarters)
    const unsigned char* __restrict__ KV,   // [N][1536]
    ushort* __restrict__ X)         // [N][512] bf16 out
{
    int n = blockIdx.x * 4 + (threadIdx.x >> 6);
    if (n >= NNODES) return;
    int l = threadIdx.x & 63;
    int cbase = l * 8;
    const ushort* yq = Y + (size_t)n * NQKVS + cbase;
    float qf[8];
    {
        bf16x8 q8 = *(const bf16x8*)yq;
#pragma unroll
        for (int j = 0; j < 8; ++j) qf[j] = bf2f((ushort)q8[j]);
    }
    float mrun = -INFINITY, ssum = 0.f;
    float acc[8] = {};
    int e0 = indptr[n], e1 = indptr[n + 1];
#if HAVE_FP8
    uint2 ka = {}, kb = {};
#define KLOAD(K_, base_) K_ = *(const uint2*)((base_) + cbase)
#else
    bf16x8 ka = {}, kb = {};
#define KLOAD(K_, base_) K_ = *(const bf16x8*)((base_) + cbase * 2)
#endif
    bf16x8 va = {}, vb = {};
    if (e0 < e1) {
        const unsigned char* r = KV + (size_t)ssrc[e0] * KVREC;
        KLOAD(ka, r);
        va = *(const bf16x8*)(r + 512 + cbase * 2);
    }
    if (e0 + 1 < e1) {
        const unsigned char* r = KV + (size_t)ssrc[e0 + 1] * KVREC;
        KLOAD(kb, r);
        vb = *(const bf16x8*)(r + 512 + cbase * 2);
    }
    for (int e = e0; e < e1; ++e) {
        auto k8 = ka; bf16x8 v8 = va;
        ka = kb; va = vb;
        int en = e + 2;
        if (en < e1) {
            const unsigned char* r = KV + (size_t)ssrc[en] * KVREC;
            KLOAD(kb, r);
            vb = *(const bf16x8*)(r + 512 + cbase * 2);
        }
        float part = 0.f;
#if HAVE_FP8
        {
            f32x2 k01 = __builtin_amdgcn_cvt_pk_f32_fp8((int)k8.x, false);
            f32x2 k23 = __builtin_amdgcn_cvt_pk_f32_fp8((int)k8.x, true);
            f32x2 k45 = __builtin_amdgcn_cvt_pk_f32_fp8((int)k8.y, false);
            f32x2 k67 = __builtin_amdgcn_cvt_pk_f32_fp8((int)k8.y, true);
            part = fmaf(qf[0], k01.x, part); part = fmaf(qf[1], k01.y, part);
            part = fmaf(qf[2], k23.x, part); part = fmaf(qf[3], k23.y, part);
            part = fmaf(qf[4], k45.x, part); part = fmaf(qf[5], k45.y, part);
            part = fmaf(qf[6], k67.x, part); part = fmaf(qf[7], k67.y, part);
        }
        const float smul = KISCALE;
#else
#pragma unroll
        for (int j = 0; j < 8; ++j) part = fmaf(qf[j], bf2f((ushort)k8[j]), part);
        const float smul = 0.125f;
#endif
        part += __shfl_xor(part, 1);
        part += __shfl_xor(part, 2);
        part += __shfl_xor(part, 4);
        float score = part * smul;
        float mnew = fmaxf(mrun, score);
        float sc = __expf(mrun - mnew);
        float p = __expf(score - mnew);
        ssum = ssum * sc + p;
#pragma unroll
        for (int j = 0; j < 8; ++j)
            acc[j] = fmaf(acc[j], sc, p * bf2f((ushort)v8[j]));
        mrun = mnew;
    }
    float inv = ssum > 0.f ? 1.f / ssum : 0.f;
    bf16x8 o8;
#pragma unroll
    for (int j = 0; j < 8; ++j) {
        float o = fmaxf(fmaf(acc[j], inv, bf2f(yq[1536 + j])), 0.f);  // + skip, ReLU
        o8[j] = (short)f2bf(o);
    }
    *(bf16x8*)(X + (size_t)n * HID + cbase) = o8;
}

// ---------------- pooling: xsumP[u][p][c] = partial sums over 64 rows ----------------
__global__ __launch_bounds__(512) void k_pool(const ushort* __restrict__ X, float* __restrict__ xsumP)
{
    int u = blockIdx.x;
    int pp = blockIdx.y;               // 0..7
    int c = threadIdx.x;
    const ushort* base = X + ((size_t)u * MM + pp * 64) * HID + c;
    float s = 0.f;
    for (int m = 0; m < 64; ++m) s += bf2f(base[(size_t)m * HID]);
    xsumP[((size_t)u * 8 + pp) * HID + c] = s;
}

// ---------------- fused: emb = xsum @ Wout + M*bout, then actor/critic head ----------------
__global__ __launch_bounds__(512) void k_embhead(
    const float* __restrict__ xsumP, const float* __restrict__ Wout,
    const float* __restrict__ bout,
    const float* __restrict__ uavs, const float* __restrict__ speeds,
    const float* __restrict__ Wc1, const float* __restrict__ bc1,
    const float* __restrict__ Wc2, const float* __restrict__ bc2,
    float* __restrict__ out)
{
    __shared__ float xs[HID];
    __shared__ float comb[67];
    __shared__ float red[128];
    int u = blockIdx.x, c = threadIdx.x;
    float s = 0.f;
#pragma unroll
    for (int p = 0; p < 8; ++p) s += xsumP[((size_t)u * 8 + p) * HID + c];
    xs[c] = s;
    __syncthreads();
    if (c < 64) {
        float a = 0.f;
        for (int i = 0; i < HID; ++i) a = fmaf(xs[i], Wout[i * 64 + c], a);
        comb[2 + c] = a + 512.0f * bout[c];
    }
    if (c == 64) { comb[0] = uavs[u * 2]; comb[1] = uavs[u * 2 + 1]; }
    if (c == 65) comb[66] = speeds[u];
    __syncthreads();
    if (c < 128) {
        float a = bc1[c];
        for (int i = 0; i < 67; ++i) a = fmaf(comb[i], Wc1[i * 128 + c], a);
        a = fmaxf(a, 0.f);
        red[c] = a * Wc2[c];
    }
    __syncthreads();
    for (int sft = 64; sft > 0; sft >>= 1) {
        if (c < sft) red[c] += red[c + sft];
        __syncthreads();
    }
    if (c == 0) {
        out[u]      = 1.0f;                 // softmax over singleton axis
        out[16 + u] = red[0] + bc2[0];
    }
}

extern "C" void kernel_launch(void* const* d_in, const int* in_sizes, int n_in,
                              void* d_out, int out_size, void* d_ws, size_t ws_size,
                              hipStream_t stream)
{
    const float* mission_coords = (const float*)d_in[0];
    const float* uavs_info      = (const float*)d_in[1];
    const float* speeds         = (const float*)d_in[2];
    const float* dist_matrix    = (const float*)d_in[3];
    const float* timetogo       = (const float*)d_in[4];
    const int*   action_mask    = (const int*)d_in[5];
    const int*   edge_index     = (const int*)d_in[6];
    const float* Wq0 = (const float*)d_in[8];  const float* bq0 = (const float*)d_in[9];
    const float* Wk0 = (const float*)d_in[10]; const float* bk0 = (const float*)d_in[11];
    const float* Wv0 = (const float*)d_in[12]; const float* bv0 = (const float*)d_in[13];
    const float* Ws0 = (const float*)d_in[14]; const float* bs0 = (const float*)d_in[15];
    const float* Wq  = (const float*)d_in[16]; const float* bq  = (const float*)d_in[17];
    const float* Wk  = (const float*)d_in[18]; const float* bk  = (const float*)d_in[19];
    const float* Wv  = (const float*)d_in[20]; const float* bv  = (const float*)d_in[21];
    const float* Ws  = (const float*)d_in[22]; const float* bs  = (const float*)d_in[23];
    const float* Wout = (const float*)d_in[24]; const float* bout = (const float*)d_in[25];
    const float* Wc1 = (const float*)d_in[30]; const float* bc1 = (const float*)d_in[31];
    const float* Wc2 = (const float*)d_in[32]; const float* bc2 = (const float*)d_in[33];
    float* out = (float*)d_out;

    const int* e_src = edge_index;
    const int* e_dst = edge_index + NEDGES;

    // ---- workspace carve ----
    char* p = (char*)d_ws;
    ushort* Ybf = (ushort*)p;  p += (size_t)NNODES * NQKVS * 2;   // 32 MB
    ushort* Xbf = (ushort*)p;  p += (size_t)NNODES * HID * 2;     // 8 MB
    ushort* Wt  = (ushort*)p;  p += (size_t)3 * NQKVS * HID * 2;  // 6 MB
    unsigned char* KV = (unsigned char*)p; p += (size_t)NNODES * KVREC; // 12 MB
    float* bcat = (float*)p;   p += (size_t)3 * NQKVS * 4;
    float* xsumP = (float*)p;  p += (size_t)UU * 8 * HID * 4;
    int* cnt    = (int*)p;     p += (size_t)NNODES * 4;           // cnt+cursor adjacent
    int* cursor = (int*)p;     p += (size_t)NNODES * 4;
    int* indptr = (int*)p;     p += (size_t)(NNODES + 1) * 4;
    int* ssrc   = (int*)p;     p += (size_t)NEDGES * 4;

    // ---- prep: weights+bias+zeroing (fused), CSR ----
    k_wtb<<<dim3(8, 8, 13), 256, 0, stream>>>(Wq, Wk, Wv, Ws, bq, bk, bv, bs,
                                              Wt, bcat, cnt);
    k_hist<<<NEDGES / 256, 256, 0, stream>>>(e_dst, cnt);
    k_scan<<<1, 1024, 0, stream>>>(cnt, indptr);
    k_scatter<<<NEDGES / 256, 256, 0, stream>>>(e_src, e_dst, indptr, cursor, ssrc);

    // ---- layer 0 (in=6, fused feature build) ----
    k_lin0<<<NNODES, 256, 0, stream>>>(mission_coords, speeds, dist_matrix, timetogo,
                                       action_mask, Wq0, bq0, Wk0, bk0, Wv0, bv0,
                                       Ws0, bs0, Ybf, KV);
    k_attn<<<NNODES / 4, 256, 0, stream>>>(indptr, ssrc, Ybf, KV, Xbf);

    // ---- layers 1..3: fused q|k|v|s MFMA GEMM + attention ----
    const int ngblocks = (NNODES / GBM) * (NQKVS / GBN);   // 1024
    for (int l = 0; l < 3; ++l) {
        k_gemm<<<ngblocks, 256, 0, stream>>>(Xbf, Wt + (size_t)l * NQKVS * HID,
                                             bcat + l * NQKVS, Ybf, KV);
        k_attn<<<NNODES / 4, 256, 0, stream>>>(indptr, ssrc, Ybf, KV, Xbf);
    }

    // ---- pooling + fused embedding/head ----
    k_pool<<<dim3(UU, 8), 512, 0, stream>>>(Xbf, xsumP);
    k_embhead<<<UU, 512, 0, stream>>>(xsumP, Wout, bout, uavs_info, speeds,
                                      Wc1, bc1, Wc2, bc2, out);
}